// Round 7
// baseline (247.862 us; speedup 1.0000x reference)
//
#include <hip/hip_runtime.h>

// Problem constants
#define BB  16
#define JJ  32
#define HH  512
#define WW  512
#define KK  9
#define PAD 3
#define OH  510
#define OW  510

// No-im2col implicit GEMM, operand-swapped: D[pixel][j] = im2col^T x W^T.
// k = u*16 + v (v padded to 16). A-fragment (input) = 8 contiguous raw
// elements, read from 4 shifted bf16 copies via two 8B LDS reads.
// B-fragment (weights) from prepacked bf16 table, held in registers.
// D is pixel-major per lane (4 consecutive px) -> float2 global stores.
#define NPIX   128
#define RROWS  8
#define NRAW   16
#define NCHUNK 18                  // 16B chunks per copy (covers i<=143)
#define CPY_PITCH 288              // 18*16; words 72 == 8 mod 32 (c-stagger)
#define ROW_PITCH 1184             // 4*288 + 32; words 296 == 8 mod 32
#define LDS_BYTES (NRAW * ROW_PITCH)   // 18944

// prepacked weight table (union with input-copy region): [32 j][10 u * 32B]
#define W_PITCH 336                // 10*32 + 16 pad; 16B multiple

typedef __bf16 bf16x8 __attribute__((ext_vector_type(8)));
typedef float  f32x4  __attribute__((ext_vector_type(4)));

__device__ __forceinline__ unsigned pack2bf(float a, float b) {
    unsigned ua = __float_as_uint(a) + 0x8000u;
    unsigned ub = __float_as_uint(b) + 0x8000u;
    return (ua >> 16) | (ub & 0xFFFF0000u);
}

__global__ __launch_bounds__(256, 5)
void conv_mfma_kernel(const float* __restrict__ in,
                      const float* __restrict__ wgt,
                      float* __restrict__ out) {
    __shared__ __align__(16) char lds[LDS_BYTES];

    const int tid  = threadIdx.x;
    const int lane = tid & 63;
    const int w    = tid >> 6;     // wave 0..3: owns 32 pixels
    const int col  = lane & 15;
    const int q    = lane >> 4;
    const int g    = q >> 1;
    const int h    = q & 1;

    const int x0 = blockIdx.x * NPIX;
    const int y0 = blockIdx.y * RROWS;
    const int bi = blockIdx.z;

    // ---- W1: pack weights -> bf16 table [j][u*16+v slots], zero-padded ----
    const float* wB = wgt + (size_t)bi * JJ * (KK * KK);
    for (int idx = tid; idx < JJ * 10; idx += 256) {
        const int j = idx / 10, u = idx - 10 * (idx / 10);
        float wv[9];
        #pragma unroll
        for (int v = 0; v < 9; ++v)
            wv[v] = (u < 9) ? wB[j * 81 + u * 9 + v] : 0.f;
        char* dst = lds + j * W_PITCH + u * 32;
        *(uint4*)dst = make_uint4(pack2bf(wv[0], wv[1]), pack2bf(wv[2], wv[3]),
                                  pack2bf(wv[4], wv[5]), pack2bf(wv[6], wv[7]));
        *(uint4*)(dst + 16) = make_uint4(pack2bf(wv[8], 0.f), 0u, 0u, 0u);
    }
    __syncthreads();

    // ---- W2: weight B-fragments to registers: bw[s][jn] ----
    // lane holds W[jn*16+col][k = s*32 + q*8 + e]  (u=2s+g, v=(q&1)*8+e)
    bf16x8 bw[5][2];
    #pragma unroll
    for (int s = 0; s < 5; ++s)
        #pragma unroll
        for (int jn = 0; jn < 2; ++jn)
            bw[s][jn] = *(const bf16x8*)(lds + (jn * 16 + col) * W_PITCH
                                             + s * 64 + q * 16);
    __syncthreads();   // weight region reused by input copies

    // ---- stage raw input rows as 4 shifted bf16 copies ----
    // copy c chunk m = elements (c+8m .. c+8m+7) of row [x0-3 .. x0+140]
    const float* inB = in + (size_t)bi * (HH * WW);
    #pragma unroll 1
    for (int idx = tid; idx < NRAW * NCHUNK; idx += 256) {
        const int rr = idx / NCHUNK;
        const int m  = idx - rr * NCHUNK;
        const int gr = y0 - PAD + rr;
        const int gc0 = x0 - PAD + 8 * m;
        const bool rok = ((unsigned)gr < (unsigned)HH);
        float el[11];
        #pragma unroll
        for (int e = 0; e < 11; ++e) {
            const int gc = gc0 + e;
            el[e] = (rok && (unsigned)gc < (unsigned)WW) ? inB[gr * WW + gc] : 0.f;
        }
        unsigned P[5], Q[5];
        #pragma unroll
        for (int i = 0; i < 5; ++i) {
            P[i] = pack2bf(el[2 * i],     el[2 * i + 1]);
            Q[i] = pack2bf(el[2 * i + 1], el[2 * i + 2]);
        }
        char* base = lds + rr * ROW_PITCH + m * 16;
        *(uint4*)(base)                 = make_uint4(P[0], P[1], P[2], P[3]);
        *(uint4*)(base + CPY_PITCH)     = make_uint4(Q[0], Q[1], Q[2], Q[3]);
        *(uint4*)(base + 2 * CPY_PITCH) = make_uint4(P[1], P[2], P[3], P[4]);
        *(uint4*)(base + 3 * CPY_PITCH) = make_uint4(Q[1], Q[2], Q[3], Q[4]);
    }
    __syncthreads();

    // ---- main loop: 8 output rows ----
    const int c    = col & 3;                 // copy index
    const int ebase = w * 32 + col + 8 * h;   // fragment start element (mt=0)
    const size_t plane = (size_t)OH * OW;

    #pragma unroll 1
    for (int r = 0; r < RROWS; ++r) {
        f32x4 acc[2][2];
        #pragma unroll
        for (int mt = 0; mt < 2; ++mt)
            #pragma unroll
            for (int jn = 0; jn < 2; ++jn)
                acc[mt][jn] = (f32x4){0.f, 0.f, 0.f, 0.f};

        #pragma unroll
        for (int s = 0; s < 5; ++s) {
            int u = 2 * s + g;
            if (u > 8) u = 0;                 // s==4,g==1: bw==0, any finite A ok
            const char* rowp = lds + (r + u) * ROW_PITCH + c * CPY_PITCH;
            #pragma unroll
            for (int mt = 0; mt < 2; ++mt) {
                const int off = (ebase + mt * 16 - c) * 2;   // 8B aligned
                const uint2 lo = *(const uint2*)(rowp + off);
                const uint2 hi = *(const uint2*)(rowp + off + 8);
                const bf16x8 af = __builtin_bit_cast(bf16x8,
                                      make_uint4(lo.x, lo.y, hi.x, hi.y));
                acc[mt][0] = __builtin_amdgcn_mfma_f32_16x16x32_bf16(af, bw[s][0], acc[mt][0], 0, 0, 0);
                acc[mt][1] = __builtin_amdgcn_mfma_f32_16x16x32_bf16(af, bw[s][1], acc[mt][1], 0, 0, 0);
            }
        }

        const int y = y0 + r;
        if (y < OH) {
            #pragma unroll
            for (int mt = 0; mt < 2; ++mt) {
                const int px = x0 + w * 32 + mt * 16 + q * 4;
                #pragma unroll
                for (int jn = 0; jn < 2; ++jn) {
                    const int j = jn * 16 + col;
                    float* op = out + (size_t)(bi * JJ + j) * plane
                                    + (size_t)y * OW + px;
                    if (px + 1 < OW)
                        *(float2*)op = make_float2(acc[mt][jn][0], acc[mt][jn][1]);
                    if (px + 3 < OW)
                        *(float2*)(op + 2) = make_float2(acc[mt][jn][2], acc[mt][jn][3]);
                }
            }
        }
    }
}

extern "C" void kernel_launch(void* const* d_in, const int* in_sizes, int n_in,
                              void* d_out, int out_size, void* d_ws, size_t ws_size,
                              hipStream_t stream) {
    const float* inp = (const float*)d_in[0];   // [16,1,512,512] f32
    const float* wgt = (const float*)d_in[1];   // [16,32,9,9]    f32
    float* out = (float*)d_out;                 // [16,32,510,510] f32

    dim3 grid(4, 64, BB);
    conv_mfma_kernel<<<grid, 256, 0, stream>>>(inp, wgt, out);
}

// Round 8
// 214.765 us; speedup vs baseline: 1.1541x; 1.1541x over previous
//
#include <hip/hip_runtime.h>

// Problem constants
#define BB  16
#define JJ  32
#define HH  512
#define WW  512
#define KK  9
#define PAD 3
#define OH  510
#define OW  510

// No-im2col implicit GEMM (round-6 orientation: A=weights, B=pixels).
// k = u*16 + v (v padded to 16). B-fragment = 8 contiguous raw input
// elements from 4 shifted bf16 copies (two 8B LDS reads, validated r7).
// NEW: stores go through an LDS D-buffer so each global store inst is
// 512B contiguous in ONE output plane (64 lanes x float2) -- attacks the
// write-locality bottleneck (measured 2.4 TB/s vs 6.5 TB/s memset).
#define NPIX   128
#define RROWS  8
#define NRAW   16
#define NCHUNK 18
#define CPY_PITCH 288              // 18*16 B
#define ROW_PITCH 1184             // 4*288 + 32
#define IN_BYTES  (NRAW * ROW_PITCH)   // 18944

#define D_PITCH   132              // floats; 4j+px banks -> 2-way (free)
#define DBUF_OFF  IN_BYTES
#define LDS_BYTES (DBUF_OFF + JJ * D_PITCH * 4)   // 35840 -> 4 blocks/CU

// raw f32 weight region (union with input+D regions, used before staging)
#define WJ_PITCH 656
#define W_RAW_BYTES (JJ * WJ_PITCH)   // 20992 <= LDS_BYTES

typedef __bf16 bf16x8 __attribute__((ext_vector_type(8)));
typedef float  f32x4  __attribute__((ext_vector_type(4)));

__device__ __forceinline__ unsigned pack2bf(float a, float b) {
    unsigned ua = __float_as_uint(a) + 0x8000u;
    unsigned ub = __float_as_uint(b) + 0x8000u;
    return (ua >> 16) | (ub & 0xFFFF0000u);
}

__global__ __launch_bounds__(256, 4)
void conv_mfma_kernel(const float* __restrict__ in,
                      const float* __restrict__ wgt,
                      float* __restrict__ out) {
    __shared__ __align__(16) char lds[LDS_BYTES];

    const int tid  = threadIdx.x;
    const int lane = tid & 63;
    const int w    = tid >> 6;
    const int col  = lane & 15;
    const int q    = lane >> 4;
    const int g    = q >> 1;
    const int h    = q & 1;

    const int x0 = blockIdx.x * NPIX;
    const int y0 = blockIdx.y * RROWS;
    const int bi = blockIdx.z;

    // ---- W1: zero + fill padded raw f32 weights [32 j][10 u][16 v] ----
    {
        const uint4 z = make_uint4(0u, 0u, 0u, 0u);
        for (int idx = tid; idx < W_RAW_BYTES / 16; idx += 256)
            *(uint4*)(lds + idx * 16) = z;
    }
    __syncthreads();
    const float* wB = wgt + (size_t)bi * JJ * (KK * KK);
    for (int idx = tid; idx < JJ * KK * KK; idx += 256) {
        const int j   = idx / (KK * KK);
        const int rem = idx - j * (KK * KK);
        const int u   = rem / KK;
        const int v   = rem - u * KK;
        *(float*)(lds + j * WJ_PITCH + u * 64 + v * 4) = wB[idx];
    }
    __syncthreads();

    // ---- W2: A fragments (weights) to registers ----
    // afrag[s][mt]: lane holds W[mt*16+col][u=2s+g][v = 8h + 0..7]
    bf16x8 afrag[5][2];
    #pragma unroll
    for (int s = 0; s < 5; ++s) {
        const int u = 2 * s + g;          // 0..9 (u=9 row zeroed)
        #pragma unroll
        for (int mt = 0; mt < 2; ++mt) {
            const char* p = lds + (mt * 16 + col) * WJ_PITCH + u * 64 + h * 32;
            const float4 fa = *(const float4*)p;
            const float4 fb = *(const float4*)(p + 16);
            const uint4 pk = make_uint4(pack2bf(fa.x, fa.y), pack2bf(fa.z, fa.w),
                                        pack2bf(fb.x, fb.y), pack2bf(fb.z, fb.w));
            afrag[s][mt] = __builtin_bit_cast(bf16x8, pk);
        }
    }
    __syncthreads();   // weight region reused below

    // ---- stage raw input rows as 4 shifted bf16 copies (r7-validated) ----
    const float* inB = in + (size_t)bi * (HH * WW);
    #pragma unroll 1
    for (int idx = tid; idx < NRAW * NCHUNK; idx += 256) {
        const int rr = idx / NCHUNK;
        const int m  = idx - rr * NCHUNK;
        const int gr = y0 - PAD + rr;
        const int gc0 = x0 - PAD + 8 * m;
        const bool rok = ((unsigned)gr < (unsigned)HH);
        float el[11];
        #pragma unroll
        for (int e = 0; e < 11; ++e) {
            const int gc = gc0 + e;
            el[e] = (rok && (unsigned)gc < (unsigned)WW) ? inB[gr * WW + gc] : 0.f;
        }
        unsigned P[5], Q[5];
        #pragma unroll
        for (int i = 0; i < 5; ++i) {
            P[i] = pack2bf(el[2 * i],     el[2 * i + 1]);
            Q[i] = pack2bf(el[2 * i + 1], el[2 * i + 2]);
        }
        char* base = lds + rr * ROW_PITCH + m * 16;
        *(uint4*)(base)                 = make_uint4(P[0], P[1], P[2], P[3]);
        *(uint4*)(base + CPY_PITCH)     = make_uint4(Q[0], Q[1], Q[2], Q[3]);
        *(uint4*)(base + 2 * CPY_PITCH) = make_uint4(P[1], P[2], P[3], P[4]);
        *(uint4*)(base + 3 * CPY_PITCH) = make_uint4(Q[1], Q[2], Q[3], Q[4]);
    }
    __syncthreads();

    // ---- main loop: 8 output rows ----
    const int ec   = col & 3;                       // copy index
    const int e0   = w * 32 + col + 8 * h;          // fragment start element
    const int boff = ec * CPY_PITCH + (e0 - ec) * 2;
    float* D = (float*)(lds + DBUF_OFF);
    const size_t plane = (size_t)OH * OW;
    float* outB = out + (size_t)bi * JJ * plane;

    #pragma unroll 1
    for (int r = 0; r < RROWS; ++r) {
        f32x4 acc00 = {0.f, 0.f, 0.f, 0.f};
        f32x4 acc01 = {0.f, 0.f, 0.f, 0.f};
        f32x4 acc10 = {0.f, 0.f, 0.f, 0.f};
        f32x4 acc11 = {0.f, 0.f, 0.f, 0.f};

        #pragma unroll
        for (int s = 0; s < 5; ++s) {
            int u = 2 * s + g;
            if (u > 8) u = 0;                 // afrag==0 there; any finite B ok
            const char* rowp = lds + (r + u) * ROW_PITCH + boff;
            const uint2 l0 = *(const uint2*)(rowp);
            const uint2 h0 = *(const uint2*)(rowp + 8);
            const uint2 l1 = *(const uint2*)(rowp + 32);
            const uint2 h1 = *(const uint2*)(rowp + 40);
            const bf16x8 b0 = __builtin_bit_cast(bf16x8, make_uint4(l0.x, l0.y, h0.x, h0.y));
            const bf16x8 b1 = __builtin_bit_cast(bf16x8, make_uint4(l1.x, l1.y, h1.x, h1.y));
            acc00 = __builtin_amdgcn_mfma_f32_16x16x32_bf16(afrag[s][0], b0, acc00, 0, 0, 0);
            acc01 = __builtin_amdgcn_mfma_f32_16x16x32_bf16(afrag[s][0], b1, acc01, 0, 0, 0);
            acc10 = __builtin_amdgcn_mfma_f32_16x16x32_bf16(afrag[s][1], b0, acc10, 0, 0, 0);
            acc11 = __builtin_amdgcn_mfma_f32_16x16x32_bf16(afrag[s][1], b1, acc11, 0, 0, 0);
        }

        // D-buffer write: row j = (mt*16 + q*4 + rg), col px (2-way banks)
        const int pxb = w * 32 + col;
        #pragma unroll
        for (int rg = 0; rg < 4; ++rg) {
            D[(q * 4 + rg) * D_PITCH + pxb]           = acc00[rg];
            D[(q * 4 + rg) * D_PITCH + pxb + 16]      = acc01[rg];
            D[(16 + q * 4 + rg) * D_PITCH + pxb]      = acc10[rg];
            D[(16 + q * 4 + rg) * D_PITCH + pxb + 16] = acc11[rg];
        }
        __syncthreads();

        // store: one plane, 512B contiguous per inst (64 lanes x float2)
        const int y = y0 + r;
        if (y < OH) {
            const int px = 2 * lane;
            const int gx = x0 + px;
            #pragma unroll
            for (int i = 0; i < 8; ++i) {
                const int j = w * 8 + i;
                const float2 v = *(const float2*)&D[j * D_PITCH + px];
                if (gx + 1 < OW)
                    *(float2*)(outB + (size_t)j * plane + (size_t)y * OW + gx) = v;
            }
        }
        __syncthreads();
    }
}

extern "C" void kernel_launch(void* const* d_in, const int* in_sizes, int n_in,
                              void* d_out, int out_size, void* d_ws, size_t ws_size,
                              hipStream_t stream) {
    const float* inp = (const float*)d_in[0];   // [16,1,512,512] f32
    const float* wgt = (const float*)d_in[1];   // [16,32,9,9]    f32
    float* out = (float*)d_out;                 // [16,32,510,510] f32

    dim3 grid(4, 64, BB);
    conv_mfma_kernel<<<grid, 256, 0, stream>>>(inp, wgt, out);
}

// Round 9
// 213.581 us; speedup vs baseline: 1.1605x; 1.0055x over previous
//
#include <hip/hip_runtime.h>

// Problem constants
#define BB  16
#define JJ  32
#define HH  512
#define WW  512
#define KK  9
#define PAD 3
#define OH  510
#define OW  510

// No-im2col implicit GEMM (round-8 structure). ONE change vs round 8:
// the two per-row barriers use raw s_barrier + lgkmcnt(0)-only waits so
// global stores are NEVER drained inside the row loop (__syncthreads
// emits s_waitcnt vmcnt(0) before s_barrier, forcing every wave to wait
// for store completion 16x per block -- the round-8 serializer).
#define NPIX   128
#define RROWS  8
#define NRAW   16
#define NCHUNK 18
#define CPY_PITCH 288              // 18*16 B
#define ROW_PITCH 1184             // 4*288 + 32
#define IN_BYTES  (NRAW * ROW_PITCH)   // 18944

#define D_PITCH   132              // floats
#define DBUF_OFF  IN_BYTES
#define LDS_BYTES (DBUF_OFF + JJ * D_PITCH * 4)   // 35840 -> 4 blocks/CU

// raw f32 weight region (union with input+D regions, used before staging)
#define WJ_PITCH 656
#define W_RAW_BYTES (JJ * WJ_PITCH)   // 20992 <= LDS_BYTES

typedef __bf16 bf16x8 __attribute__((ext_vector_type(8)));
typedef float  f32x4  __attribute__((ext_vector_type(4)));

__device__ __forceinline__ unsigned pack2bf(float a, float b) {
    unsigned ua = __float_as_uint(a) + 0x8000u;
    unsigned ub = __float_as_uint(b) + 0x8000u;
    return (ua >> 16) | (ub & 0xFFFF0000u);
}

// barrier that waits only on LDS ops -- global stores stay in flight
__device__ __forceinline__ void barrier_lds_only() {
    asm volatile("s_waitcnt lgkmcnt(0)" ::: "memory");
    __builtin_amdgcn_s_barrier();
}

__global__ __launch_bounds__(256, 4)
void conv_mfma_kernel(const float* __restrict__ in,
                      const float* __restrict__ wgt,
                      float* __restrict__ out) {
    __shared__ __align__(16) char lds[LDS_BYTES];

    const int tid  = threadIdx.x;
    const int lane = tid & 63;
    const int w    = tid >> 6;
    const int col  = lane & 15;
    const int q    = lane >> 4;
    const int g    = q >> 1;
    const int h    = q & 1;

    const int x0 = blockIdx.x * NPIX;
    const int y0 = blockIdx.y * RROWS;
    const int bi = blockIdx.z;

    // ---- W1: zero + fill padded raw f32 weights [32 j][10 u][16 v] ----
    {
        const uint4 z = make_uint4(0u, 0u, 0u, 0u);
        for (int idx = tid; idx < W_RAW_BYTES / 16; idx += 256)
            *(uint4*)(lds + idx * 16) = z;
    }
    __syncthreads();
    const float* wB = wgt + (size_t)bi * JJ * (KK * KK);
    for (int idx = tid; idx < JJ * KK * KK; idx += 256) {
        const int j   = idx / (KK * KK);
        const int rem = idx - j * (KK * KK);
        const int u   = rem / KK;
        const int v   = rem - u * KK;
        *(float*)(lds + j * WJ_PITCH + u * 64 + v * 4) = wB[idx];
    }
    __syncthreads();

    // ---- W2: A fragments (weights) to registers ----
    // afrag[s][mt]: lane holds W[mt*16+col][u=2s+g][v = 8h + 0..7]
    bf16x8 afrag[5][2];
    #pragma unroll
    for (int s = 0; s < 5; ++s) {
        const int u = 2 * s + g;          // 0..9 (u=9 row zeroed)
        #pragma unroll
        for (int mt = 0; mt < 2; ++mt) {
            const char* p = lds + (mt * 16 + col) * WJ_PITCH + u * 64 + h * 32;
            const float4 fa = *(const float4*)p;
            const float4 fb = *(const float4*)(p + 16);
            const uint4 pk = make_uint4(pack2bf(fa.x, fa.y), pack2bf(fa.z, fa.w),
                                        pack2bf(fb.x, fb.y), pack2bf(fb.z, fb.w));
            afrag[s][mt] = __builtin_bit_cast(bf16x8, pk);
        }
    }
    __syncthreads();   // weight region reused below

    // ---- stage raw input rows as 4 shifted bf16 copies ----
    const float* inB = in + (size_t)bi * (HH * WW);
    #pragma unroll 1
    for (int idx = tid; idx < NRAW * NCHUNK; idx += 256) {
        const int rr = idx / NCHUNK;
        const int m  = idx - rr * NCHUNK;
        const int gr = y0 - PAD + rr;
        const int gc0 = x0 - PAD + 8 * m;
        const bool rok = ((unsigned)gr < (unsigned)HH);
        float el[11];
        #pragma unroll
        for (int e = 0; e < 11; ++e) {
            const int gc = gc0 + e;
            el[e] = (rok && (unsigned)gc < (unsigned)WW) ? inB[gr * WW + gc] : 0.f;
        }
        unsigned P[5], Q[5];
        #pragma unroll
        for (int i = 0; i < 5; ++i) {
            P[i] = pack2bf(el[2 * i],     el[2 * i + 1]);
            Q[i] = pack2bf(el[2 * i + 1], el[2 * i + 2]);
        }
        char* base = lds + rr * ROW_PITCH + m * 16;
        *(uint4*)(base)                 = make_uint4(P[0], P[1], P[2], P[3]);
        *(uint4*)(base + CPY_PITCH)     = make_uint4(Q[0], Q[1], Q[2], Q[3]);
        *(uint4*)(base + 2 * CPY_PITCH) = make_uint4(P[1], P[2], P[3], P[4]);
        *(uint4*)(base + 3 * CPY_PITCH) = make_uint4(Q[1], Q[2], Q[3], Q[4]);
    }
    __syncthreads();

    // ---- main loop: 8 output rows ----
    const int ec   = col & 3;                       // copy index
    const int e0   = w * 32 + col + 8 * h;          // fragment start element
    const int boff = ec * CPY_PITCH + (e0 - ec) * 2;
    float* D = (float*)(lds + DBUF_OFF);
    const size_t plane = (size_t)OH * OW;
    float* outB = out + (size_t)bi * JJ * plane;

    #pragma unroll 1
    for (int r = 0; r < RROWS; ++r) {
        f32x4 acc00 = {0.f, 0.f, 0.f, 0.f};
        f32x4 acc01 = {0.f, 0.f, 0.f, 0.f};
        f32x4 acc10 = {0.f, 0.f, 0.f, 0.f};
        f32x4 acc11 = {0.f, 0.f, 0.f, 0.f};

        #pragma unroll
        for (int s = 0; s < 5; ++s) {
            int u = 2 * s + g;
            if (u > 8) u = 0;                 // afrag==0 there; any finite B ok
            const char* rowp = lds + (r + u) * ROW_PITCH + boff;
            const uint2 l0 = *(const uint2*)(rowp);
            const uint2 h0 = *(const uint2*)(rowp + 8);
            const uint2 l1 = *(const uint2*)(rowp + 32);
            const uint2 h1 = *(const uint2*)(rowp + 40);
            const bf16x8 b0 = __builtin_bit_cast(bf16x8, make_uint4(l0.x, l0.y, h0.x, h0.y));
            const bf16x8 b1 = __builtin_bit_cast(bf16x8, make_uint4(l1.x, l1.y, h1.x, h1.y));
            acc00 = __builtin_amdgcn_mfma_f32_16x16x32_bf16(afrag[s][0], b0, acc00, 0, 0, 0);
            acc01 = __builtin_amdgcn_mfma_f32_16x16x32_bf16(afrag[s][0], b1, acc01, 0, 0, 0);
            acc10 = __builtin_amdgcn_mfma_f32_16x16x32_bf16(afrag[s][1], b0, acc10, 0, 0, 0);
            acc11 = __builtin_amdgcn_mfma_f32_16x16x32_bf16(afrag[s][1], b1, acc11, 0, 0, 0);
        }

        // D-buffer write: row j = (mt*16 + q*4 + rg), col px
        const int pxb = w * 32 + col;
        #pragma unroll
        for (int rg = 0; rg < 4; ++rg) {
            D[(q * 4 + rg) * D_PITCH + pxb]           = acc00[rg];
            D[(q * 4 + rg) * D_PITCH + pxb + 16]      = acc01[rg];
            D[(16 + q * 4 + rg) * D_PITCH + pxb]      = acc10[rg];
            D[(16 + q * 4 + rg) * D_PITCH + pxb + 16] = acc11[rg];
        }
        barrier_lds_only();   // D visible; stores from prior rows still in flight

        // store: one plane, 512B contiguous per inst (64 lanes x float2)
        const int y = y0 + r;
        if (y < OH) {
            const int px = 2 * lane;
            const int gx = x0 + px;
            #pragma unroll
            for (int i = 0; i < 8; ++i) {
                const int j = w * 8 + i;
                const float2 v = *(const float2*)&D[j * D_PITCH + px];
                if (gx + 1 < OW)
                    *(float2*)(outB + (size_t)j * plane + (size_t)y * OW + gx) = v;
            }
        }
        barrier_lds_only();   // D-reads done; next row may overwrite D
    }
}

extern "C" void kernel_launch(void* const* d_in, const int* in_sizes, int n_in,
                              void* d_out, int out_size, void* d_ws, size_t ws_size,
                              hipStream_t stream) {
    const float* inp = (const float*)d_in[0];   // [16,1,512,512] f32
    const float* wgt = (const float*)d_in[1];   // [16,32,9,9]    f32
    float* out = (float*)d_out;                 // [16,32,510,510] f32

    dim3 grid(4, 64, BB);
    conv_mfma_kernel<<<grid, 256, 0, stream>>>(inp, wgt, out);
}

// Round 10
// 178.577 us; speedup vs baseline: 1.3880x; 1.1960x over previous
//
#include <hip/hip_runtime.h>

// Problem constants
#define BB  16
#define JJ  32
#define HH  512
#define WW  512
#define KK  9
#define PAD 3
#define OH  510
#define OW  510

// No-im2col implicit GEMM (round-9 structure). ONE change vs round 9:
// XCD-grouping block swizzle. The 4 x-tiles of each (yt,bi) group are
// placed on the SAME XCD in consecutive dispatch slots (id%8 = XCD
// round-robin), so the 4 x-segments of every output plane-row are
// written into one L2/MALL within microseconds -> full 2040B rows
// assembled before eviction -> DRAM row-sized write bursts (attacks
// measured 2.5 TB/s effective write BW vs 6.6 TB/s memset).
#define NPIX   128
#define RROWS  8
#define NRAW   16
#define NCHUNK 18
#define CPY_PITCH 288              // 18*16 B
#define ROW_PITCH 1184             // 4*288 + 32
#define IN_BYTES  (NRAW * ROW_PITCH)   // 18944

#define D_PITCH   132              // floats
#define DBUF_OFF  IN_BYTES
#define LDS_BYTES (DBUF_OFF + JJ * D_PITCH * 4)   // 35840 -> 4 blocks/CU

// raw f32 weight region (union with input+D regions, used before staging)
#define WJ_PITCH 656
#define W_RAW_BYTES (JJ * WJ_PITCH)   // 20992 <= LDS_BYTES

typedef __bf16 bf16x8 __attribute__((ext_vector_type(8)));
typedef float  f32x4  __attribute__((ext_vector_type(4)));

__device__ __forceinline__ unsigned pack2bf(float a, float b) {
    unsigned ua = __float_as_uint(a) + 0x8000u;
    unsigned ub = __float_as_uint(b) + 0x8000u;
    return (ua >> 16) | (ub & 0xFFFF0000u);
}

// barrier that waits only on LDS ops -- global stores stay in flight
__device__ __forceinline__ void barrier_lds_only() {
    asm volatile("s_waitcnt lgkmcnt(0)" ::: "memory");
    __builtin_amdgcn_s_barrier();
}

__global__ __launch_bounds__(256, 4)
void conv_mfma_kernel(const float* __restrict__ in,
                      const float* __restrict__ wgt,
                      float* __restrict__ out) {
    __shared__ __align__(16) char lds[LDS_BYTES];

    const int tid  = threadIdx.x;
    const int lane = tid & 63;
    const int w    = tid >> 6;
    const int col  = lane & 15;
    const int q    = lane >> 4;
    const int g    = q >> 1;
    const int h    = q & 1;

    // ---- XCD-grouping swizzle: 4 x-tiles of (yt,bi) -> same XCD ----
    // id%8 = XCD (round-robin heuristic). ids {xcd + 8*(4*g3 + xt)} are
    // consecutive slots on XCD 'xcd'; G = g3*8 + xcd picks (yt,bi).
    {
    }
    const int id  = blockIdx.x;          // flat 0..4095
    const int xcd = id & 7;
    const int xt  = (id >> 3) & 3;
    const int G   = ((id >> 5) << 3) + xcd;   // 0..1023
    const int x0  = xt * NPIX;
    const int y0  = (G & 63) * RROWS;
    const int bi  = G >> 6;

    // ---- W1: zero + fill padded raw f32 weights [32 j][10 u][16 v] ----
    {
        const uint4 z = make_uint4(0u, 0u, 0u, 0u);
        for (int idx = tid; idx < W_RAW_BYTES / 16; idx += 256)
            *(uint4*)(lds + idx * 16) = z;
    }
    __syncthreads();
    const float* wB = wgt + (size_t)bi * JJ * (KK * KK);
    for (int idx = tid; idx < JJ * KK * KK; idx += 256) {
        const int j   = idx / (KK * KK);
        const int rem = idx - j * (KK * KK);
        const int u   = rem / KK;
        const int v   = rem - u * KK;
        *(float*)(lds + j * WJ_PITCH + u * 64 + v * 4) = wB[idx];
    }
    __syncthreads();

    // ---- W2: A fragments (weights) to registers ----
    bf16x8 afrag[5][2];
    #pragma unroll
    for (int s = 0; s < 5; ++s) {
        const int u = 2 * s + g;          // 0..9 (u=9 row zeroed)
        #pragma unroll
        for (int mt = 0; mt < 2; ++mt) {
            const char* p = lds + (mt * 16 + col) * WJ_PITCH + u * 64 + h * 32;
            const float4 fa = *(const float4*)p;
            const float4 fb = *(const float4*)(p + 16);
            const uint4 pk = make_uint4(pack2bf(fa.x, fa.y), pack2bf(fa.z, fa.w),
                                        pack2bf(fb.x, fb.y), pack2bf(fb.z, fb.w));
            afrag[s][mt] = __builtin_bit_cast(bf16x8, pk);
        }
    }
    __syncthreads();   // weight region reused below

    // ---- stage raw input rows as 4 shifted bf16 copies ----
    const float* inB = in + (size_t)bi * (HH * WW);
    #pragma unroll 1
    for (int idx = tid; idx < NRAW * NCHUNK; idx += 256) {
        const int rr = idx / NCHUNK;
        const int m  = idx - rr * NCHUNK;
        const int gr = y0 - PAD + rr;
        const int gc0 = x0 - PAD + 8 * m;
        const bool rok = ((unsigned)gr < (unsigned)HH);
        float el[11];
        #pragma unroll
        for (int e = 0; e < 11; ++e) {
            const int gc = gc0 + e;
            el[e] = (rok && (unsigned)gc < (unsigned)WW) ? inB[gr * WW + gc] : 0.f;
        }
        unsigned P[5], Q[5];
        #pragma unroll
        for (int i = 0; i < 5; ++i) {
            P[i] = pack2bf(el[2 * i],     el[2 * i + 1]);
            Q[i] = pack2bf(el[2 * i + 1], el[2 * i + 2]);
        }
        char* base = lds + rr * ROW_PITCH + m * 16;
        *(uint4*)(base)                 = make_uint4(P[0], P[1], P[2], P[3]);
        *(uint4*)(base + CPY_PITCH)     = make_uint4(Q[0], Q[1], Q[2], Q[3]);
        *(uint4*)(base + 2 * CPY_PITCH) = make_uint4(P[1], P[2], P[3], P[4]);
        *(uint4*)(base + 3 * CPY_PITCH) = make_uint4(Q[1], Q[2], Q[3], Q[4]);
    }
    __syncthreads();

    // ---- main loop: 8 output rows ----
    const int ec   = col & 3;                       // copy index
    const int e0   = w * 32 + col + 8 * h;          // fragment start element
    const int boff = ec * CPY_PITCH + (e0 - ec) * 2;
    float* D = (float*)(lds + DBUF_OFF);
    const size_t plane = (size_t)OH * OW;
    float* outB = out + (size_t)bi * JJ * plane;

    #pragma unroll 1
    for (int r = 0; r < RROWS; ++r) {
        f32x4 acc00 = {0.f, 0.f, 0.f, 0.f};
        f32x4 acc01 = {0.f, 0.f, 0.f, 0.f};
        f32x4 acc10 = {0.f, 0.f, 0.f, 0.f};
        f32x4 acc11 = {0.f, 0.f, 0.f, 0.f};

        #pragma unroll
        for (int s = 0; s < 5; ++s) {
            int u = 2 * s + g;
            if (u > 8) u = 0;                 // afrag==0 there; any finite B ok
            const char* rowp = lds + (r + u) * ROW_PITCH + boff;
            const uint2 l0 = *(const uint2*)(rowp);
            const uint2 h0 = *(const uint2*)(rowp + 8);
            const uint2 l1 = *(const uint2*)(rowp + 32);
            const uint2 h1 = *(const uint2*)(rowp + 40);
            const bf16x8 b0 = __builtin_bit_cast(bf16x8, make_uint4(l0.x, l0.y, h0.x, h0.y));
            const bf16x8 b1 = __builtin_bit_cast(bf16x8, make_uint4(l1.x, l1.y, h1.x, h1.y));
            acc00 = __builtin_amdgcn_mfma_f32_16x16x32_bf16(afrag[s][0], b0, acc00, 0, 0, 0);
            acc01 = __builtin_amdgcn_mfma_f32_16x16x32_bf16(afrag[s][0], b1, acc01, 0, 0, 0);
            acc10 = __builtin_amdgcn_mfma_f32_16x16x32_bf16(afrag[s][1], b0, acc10, 0, 0, 0);
            acc11 = __builtin_amdgcn_mfma_f32_16x16x32_bf16(afrag[s][1], b1, acc11, 0, 0, 0);
        }

        // D-buffer write: row j = (mt*16 + q*4 + rg), col px
        const int pxb = w * 32 + col;
        #pragma unroll
        for (int rg = 0; rg < 4; ++rg) {
            D[(q * 4 + rg) * D_PITCH + pxb]           = acc00[rg];
            D[(q * 4 + rg) * D_PITCH + pxb + 16]      = acc01[rg];
            D[(16 + q * 4 + rg) * D_PITCH + pxb]      = acc10[rg];
            D[(16 + q * 4 + rg) * D_PITCH + pxb + 16] = acc11[rg];
        }
        barrier_lds_only();   // D visible; stores stay in flight

        // store: one plane, 512B contiguous per inst (64 lanes x float2)
        const int y = y0 + r;
        if (y < OH) {
            const int px = 2 * lane;
            const int gx = x0 + px;
            #pragma unroll
            for (int i = 0; i < 8; ++i) {
                const int j = w * 8 + i;
                const float2 v = *(const float2*)&D[j * D_PITCH + px];
                if (gx + 1 < OW)
                    *(float2*)(outB + (size_t)j * plane + (size_t)y * OW + gx) = v;
            }
        }
        barrier_lds_only();   // D-reads done; next row may overwrite D
    }
}

extern "C" void kernel_launch(void* const* d_in, const int* in_sizes, int n_in,
                              void* d_out, int out_size, void* d_ws, size_t ws_size,
                              hipStream_t stream) {
    const float* inp = (const float*)d_in[0];   // [16,1,512,512] f32
    const float* wgt = (const float*)d_in[1];   // [16,32,9,9]    f32
    float* out = (float*)d_out;                 // [16,32,510,510] f32

    conv_mfma_kernel<<<dim3(4096), 256, 0, stream>>>(inp, wgt, out);
}